// Round 7
// baseline (264.266 us; speedup 1.0000x reference)
//
#include <hip/hip_runtime.h>

#define T_DIM 1024
#define D_DIM 64
#define WIN   128
#define TILE  64       // output rows per band block
#define KROWS 192      // staged rows = TILE + WIN
#define NT    12       // KROWS/16 col-tiles
#define NTHR  256      // 4 waves
#define NBLK  512      // 32 (b,h) * 16 tiles
#define NBH   32

typedef __attribute__((ext_vector_type(8))) short short8;
typedef __attribute__((ext_vector_type(4))) float f32x4;

__device__ __forceinline__ unsigned int pack2bf(float a, float b) {
  unsigned int ua = __float_as_uint(a);
  unsigned int ub = __float_as_uint(b);
  ua = (ua + 0x7fffu + ((ua >> 16) & 1u)) >> 16;   // RNE f32->bf16
  ub = (ub + 0x7fffu + ((ub >> 16) & 1u)) >> 16;
  return ua | (ub << 16);
}

__device__ __forceinline__ float bf2f(unsigned short b) {
  return __uint_as_float(((unsigned int)b) << 16);
}

// ---------------------------------------------------------------------------
// Stats: 1 block per (b,h). Stage all 1024 normalized rows (bf16) in LDS,
// sliding-window scan: S_i = U_i . P_i,  P_i = sum_{j in [i-128,i]} U_j.
// Writes final fitness_i = invden_i / sum(invden) to ws.
// ---------------------------------------------------------------------------
__global__ __launch_bounds__(NTHR, 1)
void stats_kernel(const float* __restrict__ E, float* __restrict__ fitws)
{
  __shared__ unsigned short Ubuf[T_DIM * D_DIM];   // 128 KB
  __shared__ float inv[T_DIM];
  __shared__ float red[4];

  const int tid = threadIdx.x, lane = tid & 63, wv = tid >> 6;
  const int bh = blockIdx.x;
  const float* Ebh = E + (size_t)bh * (T_DIM * D_DIM);

  // stage + normalize: 8 threads per row
  for (int it = 0; it < (T_DIM * 8) / NTHR; ++it) {  // 32 iters
    int u = tid + it * NTHR;
    int r = u >> 3, c = u & 7;
    const float4 f0 = *(const float4*)(Ebh + r * D_DIM + c * 8);
    const float4 f1 = *(const float4*)(Ebh + r * D_DIM + c * 8 + 4);
    float ss = f0.x*f0.x + f0.y*f0.y + f0.z*f0.z + f0.w*f0.w
             + f1.x*f1.x + f1.y*f1.y + f1.z*f1.z + f1.w*f1.w;
    ss += __shfl_xor(ss, 1);
    ss += __shfl_xor(ss, 2);
    ss += __shfl_xor(ss, 4);
    float rn = rsqrtf(ss + 1e-16f);
    uint4 w;
    w.x = pack2bf(f0.x*rn, f0.y*rn); w.y = pack2bf(f0.z*rn, f0.w*rn);
    w.z = pack2bf(f1.x*rn, f1.y*rn); w.w = pack2bf(f1.z*rn, f1.w*rn);
    *(uint4*)&Ubuf[r * D_DIM + c * 8] = w;
  }
  __syncthreads();

  // wave wv owns rows [wv*256, wv*256+256); lane = dim
  const int r0 = wv * 256;
  float P = 0.f;
  for (int j = r0 - 129; j < r0; ++j)        // invariant: P = sum_{max(0,i-129)}^{i-1}
    if (j >= 0) P += bf2f(Ubuf[j * D_DIM + lane]);
  float mysum = 0.f;
  for (int i = r0; i < r0 + 256; ++i) {
    float u = bf2f(Ubuf[i * D_DIM + lane]);
    P += u;
    if (i >= 129) P -= bf2f(Ubuf[(i - 129) * D_DIM + lane]);
    float s = u * P;
    #pragma unroll
    for (int m = 1; m < 64; m <<= 1) s += __shfl_xor(s, m);
    float id = 2048.f / (2048.f + s);        // 1/denom  (2T = 2048)
    if (lane == 0) inv[i] = id;
    mysum += id;                             // identical in all lanes
  }
  if (lane == 0) red[wv] = mysum;
  __syncthreads();
  const float rtot = 1.0f / (red[0] + red[1] + red[2] + red[3]);
  for (int i = tid; i < T_DIM; i += NTHR)
    fitws[bh * T_DIM + i] = inv[i] * rtot;
}

// ---------------------------------------------------------------------------
// Band: stage normalized bf16 rows, swapped MFMA (D = K.Q^T: lane holds 4
// consecutive j for fixed i), softmax in registers, f32x4 band stores +
// disjoint zero stores = each output element written exactly once.
// ---------------------------------------------------------------------------
__global__ __launch_bounds__(NTHR, 2)
void band_kernel(const float* __restrict__ E, const float* __restrict__ fitws,
                 float* __restrict__ out)
{
  __shared__ uint4 Kb4[KROWS * 8];           // 24 KB, swizzled 16B units

  const int tid = threadIdx.x, lane = tid & 63, wv = tid >> 6;
  const int blk = blockIdx.x, bh = blk >> 4, base = (blk & 15) * TILE;
  const float* Ebh = E + (size_t)bh * (T_DIM * D_DIM);

  // stage rows [base-128, base+63] normalized bf16, swizzled
  #pragma unroll
  for (int it = 0; it < (KROWS * 8) / NTHR; ++it) {   // 6 iters
    int u = tid + it * NTHR;
    int r = u >> 3, c = u & 7;
    int gr = base - WIN + r;
    uint4 w = make_uint4(0u, 0u, 0u, 0u);
    if (gr >= 0) {
      const float4 f0 = *(const float4*)(Ebh + gr * D_DIM + c * 8);
      const float4 f1 = *(const float4*)(Ebh + gr * D_DIM + c * 8 + 4);
      float ss = f0.x*f0.x + f0.y*f0.y + f0.z*f0.z + f0.w*f0.w
               + f1.x*f1.x + f1.y*f1.y + f1.z*f1.z + f1.w*f1.w;
      ss += __shfl_xor(ss, 1);
      ss += __shfl_xor(ss, 2);
      ss += __shfl_xor(ss, 4);
      float rn = rsqrtf(ss + 1e-16f);
      w.x = pack2bf(f0.x*rn, f0.y*rn); w.y = pack2bf(f0.z*rn, f0.w*rn);
      w.z = pack2bf(f1.x*rn, f1.y*rn); w.w = pack2bf(f1.z*rn, f1.w*rn);
    }
    Kb4[(r << 3) + (c ^ (r & 7))] = w;
  }
  __syncthreads();

  // zero pass: thread owns uint4-col q=tid for all 64 rows; drains under MFMA
  {
    const f32x4 z = {0.f, 0.f, 0.f, 0.f};
    f32x4* outq = (f32x4*)out + ((size_t)bh * T_DIM + base) * (T_DIM / 4);
    const int q = tid;
    #pragma unroll 4
    for (int r = 0; r < TILE; ++r) {
      int i = base + r;
      int q0 = (i >= WIN) ? ((i - WIN) >> 2) : 0;
      int q1 = i >> 2;
      if (q < q0 || q > q1)
        __builtin_nontemporal_store(z, &outq[r * (T_DIM / 4) + q]);
    }
  }

  const short8* KbF = (const short8*)Kb4;
  const int mrow = lane & 15, kg = lane >> 4;
  const int i_local = wv * 16 + mrow;        // this lane's output row
  const int i_g = base + i_local;

  // Q fragment (operand 2 -> D cols = i)
  const int qr = WIN + i_local;
  short8 b0 = KbF[(qr << 3) + (kg ^ (qr & 7))];
  short8 b1 = KbF[(qr << 3) + ((kg + 4) ^ (qr & 7))];

  f32x4 acc[NT];
  #pragma unroll
  for (int t = 0; t < NT; ++t) {
    if (t < wv || t > wv + 8) continue;
    int br = t * 16 + mrow;                  // K rows (operand 1 -> D rows = j)
    short8 a0 = KbF[(br << 3) + (kg ^ (br & 7))];
    short8 a1 = KbF[(br << 3) + ((kg + 4) ^ (br & 7))];
    f32x4 ca = {0.f, 0.f, 0.f, 0.f};
    ca = __builtin_amdgcn_mfma_f32_16x16x32_bf16(a0, b0, ca, 0, 0, 0);
    ca = __builtin_amdgcn_mfma_f32_16x16x32_bf16(a1, b1, ca, 0, 0, 0);
    acc[t] = ca;                             // reg g: rj = t*16+kg*4+g, col i
  }

  const float fh = 0.5f * fitws[bh * T_DIM + i_g];   // 0.5*fitness_i

  // masked value + in-register softmax (reduce over kg: 2 shfls)
  float mx = -1e30f, esum = 0.f;
  #pragma unroll
  for (int t = 0; t < NT; ++t) {
    if (t < wv || t > wv + 8) continue;
    #pragma unroll
    for (int g = 0; g < 4; ++g) {
      int rj = t * 16 + kg * 4 + g;
      bool valid = (rj >= i_local) && (rj <= i_local + WIN)
                && (base - WIN + rj >= 0);
      float v = valid ? fh * acc[t][g] + fh : -1e30f;  // (corr+1)*0.5*fit
      acc[t][g] = v;
      mx = fmaxf(mx, v);
    }
  }
  mx = fmaxf(mx, __shfl_xor(mx, 16));
  mx = fmaxf(mx, __shfl_xor(mx, 32));
  #pragma unroll
  for (int t = 0; t < NT; ++t) {
    if (t < wv || t > wv + 8) continue;
    #pragma unroll
    for (int g = 0; g < 4; ++g) {
      float e = __expf(acc[t][g] - mx);      // masked -> 0
      acc[t][g] = e;
      esum += e;
    }
  }
  esum += __shfl_xor(esum, 16);
  esum += __shfl_xor(esum, 32);
  const float rinv = 1.0f / esum;

  // band cover stores: f32x4 chunks within [jlo, jhi] (uint4-aligned)
  const int jlo = (i_g >= WIN) ? ((i_g - WIN) & ~3) : 0;
  const int jhi = (i_g & ~3) + 3;
  float* outrow = out + ((size_t)bh * T_DIM + i_g) * T_DIM;
  #pragma unroll
  for (int t = 0; t < NT; ++t) {
    if (t < wv || t > wv + 8) continue;
    int jb = base - WIN + t * 16 + kg * 4;   // 4-aligned global j of chunk
    if (jb >= jlo && jb + 3 <= jhi) {
      f32x4 val = {acc[t][0] * rinv, acc[t][1] * rinv,
                   acc[t][2] * rinv, acc[t][3] * rinv};
      __builtin_nontemporal_store(val, (f32x4*)(outrow + jb));
    }
  }
}

extern "C" void kernel_launch(void* const* d_in, const int* in_sizes, int n_in,
                              void* d_out, int out_size, void* d_ws, size_t ws_size,
                              hipStream_t stream) {
  const float* E = (const float*)d_in[0];
  float* out = (float*)d_out;
  float* fitws = (float*)d_ws;               // 32*1024 floats
  hipLaunchKernelGGL(stats_kernel, dim3(NBH), dim3(NTHR), 0, stream, E, fitws);
  hipLaunchKernelGGL(band_kernel, dim3(NBLK), dim3(NTHR), 0, stream, E, fitws, out);
}

// Round 8
// 161.521 us; speedup vs baseline: 1.6361x; 1.6361x over previous
//
#include <hip/hip_runtime.h>

#define T_DIM 1024
#define D_DIM 64
#define WIN   128
#define TILE  64       // output rows per block
#define KROWS 192      // staged rows = TILE + WIN
#define NT    12       // KROWS/16 col-tiles
#define NTHR  256      // 4 waves
#define NBLK  512      // 32 (b,h) * 16 tiles
#define NBH   32

typedef __attribute__((ext_vector_type(8))) short short8;
typedef __attribute__((ext_vector_type(4))) float f32x4;

__device__ __forceinline__ unsigned int pack2bf(float a, float b) {
  unsigned int ua = __float_as_uint(a);
  unsigned int ub = __float_as_uint(b);
  ua = (ua + 0x7fffu + ((ua >> 16) & 1u)) >> 16;   // RNE f32->bf16
  ub = (ub + 0x7fffu + ((ub >> 16) & 1u)) >> 16;
  return ua | (ub << 16);
}

// Stage rows [base-128, base+63] NORMALIZED (U = E/|E|) as swizzled bf16.
__device__ __forceinline__ void stage_norm(const float* __restrict__ Ebh,
                                           int base, uint4* Kb4, int tid)
{
  #pragma unroll
  for (int it = 0; it < (KROWS * 8) / NTHR; ++it) {   // 6 iters
    int u = tid + it * NTHR;
    int r = u >> 3, c = u & 7;
    int gr = base - WIN + r;
    uint4 w = make_uint4(0u, 0u, 0u, 0u);
    if (gr >= 0) {
      const float4 f0 = *(const float4*)(Ebh + gr * D_DIM + c * 8);
      const float4 f1 = *(const float4*)(Ebh + gr * D_DIM + c * 8 + 4);
      float ss = f0.x*f0.x + f0.y*f0.y + f0.z*f0.z + f0.w*f0.w
               + f1.x*f1.x + f1.y*f1.y + f1.z*f1.z + f1.w*f1.w;
      ss += __shfl_xor(ss, 1);
      ss += __shfl_xor(ss, 2);
      ss += __shfl_xor(ss, 4);
      float rn = rsqrtf(ss + 1e-16f);
      w.x = pack2bf(f0.x*rn, f0.y*rn); w.y = pack2bf(f0.z*rn, f0.w*rn);
      w.z = pack2bf(f1.x*rn, f1.y*rn); w.w = pack2bf(f1.z*rn, f1.w*rn);
    }
    Kb4[(r << 3) + (c ^ (r & 7))] = w;
  }
}

// ---------------------------------------------------------------------------
// Stats: 512 blocks. Swapped MFMA -> S_i in-register (2 shfls) -> invden ->
// per-block partial sum of invden. Plain store to ws (no init needed).
// ---------------------------------------------------------------------------
__global__ __launch_bounds__(NTHR, 2)
void stats_kernel(const float* __restrict__ E, float* __restrict__ partials)
{
  __shared__ uint4 Kb4[KROWS * 8];           // 24 KB
  __shared__ float wpart[4];

  const int tid = threadIdx.x, lane = tid & 63, wv = tid >> 6;
  const int blk = blockIdx.x, bh = blk >> 4, base = (blk & 15) * TILE;
  const float* Ebh = E + (size_t)bh * (T_DIM * D_DIM);

  stage_norm(Ebh, base, Kb4, tid);
  __syncthreads();

  const short8* KbF = (const short8*)Kb4;
  const int mrow = lane & 15, kg = lane >> 4;
  const int i_local = wv * 16 + mrow;

  const int qr = WIN + i_local;              // Q fragment (D cols = i)
  short8 b0 = KbF[(qr << 3) + (kg ^ (qr & 7))];
  short8 b1 = KbF[(qr << 3) + ((kg + 4) ^ (qr & 7))];

  float sacc = 0.f;
  #pragma unroll
  for (int t = 0; t < NT; ++t) {
    if (t < wv || t > wv + 8) continue;      // no valid (i,j) outside
    int br = t * 16 + mrow;                  // K rows (D rows = j)
    short8 a0 = KbF[(br << 3) + (kg ^ (br & 7))];
    short8 a1 = KbF[(br << 3) + ((kg + 4) ^ (br & 7))];
    f32x4 ca = {0.f, 0.f, 0.f, 0.f};
    ca = __builtin_amdgcn_mfma_f32_16x16x32_bf16(a0, b0, ca, 0, 0, 0);
    ca = __builtin_amdgcn_mfma_f32_16x16x32_bf16(a1, b1, ca, 0, 0, 0);
    #pragma unroll
    for (int g = 0; g < 4; ++g) {
      int rj = t * 16 + kg * 4 + g;
      bool valid = (rj >= i_local) && (rj <= i_local + WIN)
                && (base - WIN + rj >= 0);
      sacc += valid ? ca[g] : 0.f;
    }
  }
  sacc += __shfl_xor(sacc, 16);
  sacc += __shfl_xor(sacc, 32);              // S_i in all lanes
  float v = (kg == 0) ? 2048.f / (2048.f + sacc) : 0.f;   // invden (2T=2048)
  #pragma unroll
  for (int m = 1; m < 64; m <<= 1) v += __shfl_xor(v, m);
  if (lane == 0) wpart[wv] = v;
  __syncthreads();
  if (tid == 0) partials[blk] = wpart[0] + wpart[1] + wpart[2] + wpart[3];
}

// ---------------------------------------------------------------------------
// Band: swapped MFMA, local invden (2 shfls), softmax in registers,
// disjoint zero pass + f32x4 band-cover stores (each elem written once).
// ---------------------------------------------------------------------------
__global__ __launch_bounds__(NTHR, 2)
void band_kernel(const float* __restrict__ E, const float* __restrict__ partials,
                 float* __restrict__ out)
{
  __shared__ uint4 Kb4[KROWS * 8];           // 24 KB
  __shared__ float s_rsum;

  const int tid = threadIdx.x, lane = tid & 63, wv = tid >> 6;
  const int blk = blockIdx.x, bh = blk >> 4, base = (blk & 15) * TILE;
  const float* Ebh = E + (size_t)bh * (T_DIM * D_DIM);

  // rsum = 1 / sum of this bh's 16 partials
  if (tid < 16) {
    float v = partials[(bh << 4) + tid];
    #pragma unroll
    for (int m = 1; m < 16; m <<= 1) v += __shfl_xor(v, m);
    if (tid == 0) s_rsum = 1.0f / v;
  }

  stage_norm(Ebh, base, Kb4, tid);
  __syncthreads();

  // zero pass: thread owns uint4-col q=tid for all 64 rows; drains under MFMA
  {
    const f32x4 z = {0.f, 0.f, 0.f, 0.f};
    f32x4* outq = (f32x4*)out + ((size_t)bh * T_DIM + base) * (T_DIM / 4);
    const int q = tid;
    #pragma unroll 4
    for (int r = 0; r < TILE; ++r) {
      int i = base + r;
      int q0 = (i >= WIN) ? ((i - WIN) >> 2) : 0;
      int q1 = i >> 2;
      if (q < q0 || q > q1)
        __builtin_nontemporal_store(z, &outq[r * (T_DIM / 4) + q]);
    }
  }

  const short8* KbF = (const short8*)Kb4;
  const int mrow = lane & 15, kg = lane >> 4;
  const int i_local = wv * 16 + mrow;
  const int i_g = base + i_local;

  const int qr = WIN + i_local;              // Q fragment (D cols = i)
  short8 b0 = KbF[(qr << 3) + (kg ^ (qr & 7))];
  short8 b1 = KbF[(qr << 3) + ((kg + 4) ^ (qr & 7))];

  f32x4 acc[NT];
  float sacc = 0.f;
  #pragma unroll
  for (int t = 0; t < NT; ++t) {
    if (t < wv || t > wv + 8) continue;
    int br = t * 16 + mrow;                  // K rows (D rows = j)
    short8 a0 = KbF[(br << 3) + (kg ^ (br & 7))];
    short8 a1 = KbF[(br << 3) + ((kg + 4) ^ (br & 7))];
    f32x4 ca = {0.f, 0.f, 0.f, 0.f};
    ca = __builtin_amdgcn_mfma_f32_16x16x32_bf16(a0, b0, ca, 0, 0, 0);
    ca = __builtin_amdgcn_mfma_f32_16x16x32_bf16(a1, b1, ca, 0, 0, 0);
    acc[t] = ca;                             // reg g: rj = t*16+kg*4+g, col i
    #pragma unroll
    for (int g = 0; g < 4; ++g) {
      int rj = t * 16 + kg * 4 + g;
      bool valid = (rj >= i_local) && (rj <= i_local + WIN)
                && (base - WIN + rj >= 0);
      sacc += valid ? ca[g] : 0.f;
    }
  }
  sacc += __shfl_xor(sacc, 16);
  sacc += __shfl_xor(sacc, 32);              // S_i
  const float fh = 0.5f * (2048.f / (2048.f + sacc)) * s_rsum;  // 0.5*fitness

  // masked value + in-register softmax (reduce over kg: 2 shfls)
  float mx = -1e30f, esum = 0.f;
  #pragma unroll
  for (int t = 0; t < NT; ++t) {
    if (t < wv || t > wv + 8) continue;
    #pragma unroll
    for (int g = 0; g < 4; ++g) {
      int rj = t * 16 + kg * 4 + g;
      bool valid = (rj >= i_local) && (rj <= i_local + WIN)
                && (base - WIN + rj >= 0);
      float v = valid ? fh * acc[t][g] + fh : -1e30f;  // (corr+1)*0.5*fit
      acc[t][g] = v;
      mx = fmaxf(mx, v);
    }
  }
  mx = fmaxf(mx, __shfl_xor(mx, 16));
  mx = fmaxf(mx, __shfl_xor(mx, 32));
  #pragma unroll
  for (int t = 0; t < NT; ++t) {
    if (t < wv || t > wv + 8) continue;
    #pragma unroll
    for (int g = 0; g < 4; ++g) {
      float e = __expf(acc[t][g] - mx);      // masked -> 0
      acc[t][g] = e;
      esum += e;
    }
  }
  esum += __shfl_xor(esum, 16);
  esum += __shfl_xor(esum, 32);
  const float rinv = 1.0f / esum;

  // band cover stores: f32x4 chunks within [jlo, jhi] (uint4-aligned)
  const int jlo = (i_g >= WIN) ? ((i_g - WIN) & ~3) : 0;
  const int jhi = (i_g & ~3) + 3;
  float* outrow = out + ((size_t)bh * T_DIM + i_g) * T_DIM;
  #pragma unroll
  for (int t = 0; t < NT; ++t) {
    if (t < wv || t > wv + 8) continue;
    int jb = base - WIN + t * 16 + kg * 4;   // 4-aligned global j of chunk
    if (jb >= jlo && jb + 3 <= jhi) {
      f32x4 val = {acc[t][0] * rinv, acc[t][1] * rinv,
                   acc[t][2] * rinv, acc[t][3] * rinv};
      __builtin_nontemporal_store(val, (f32x4*)(outrow + jb));
    }
  }
}

extern "C" void kernel_launch(void* const* d_in, const int* in_sizes, int n_in,
                              void* d_out, int out_size, void* d_ws, size_t ws_size,
                              hipStream_t stream) {
  const float* E = (const float*)d_in[0];
  float* out = (float*)d_out;
  float* partials = (float*)d_ws;            // 512 floats used
  hipLaunchKernelGGL(stats_kernel, dim3(NBLK), dim3(NTHR), 0, stream, E, partials);
  hipLaunchKernelGGL(band_kernel, dim3(NBLK), dim3(NTHR), 0, stream, E, partials, out);
}